// Round 9
// baseline (22.243 us; speedup 1.0000x reference)
//
#include <hip/hip_runtime.h>

#define BATCH 4096
#define INS   256
#define OUTS  256
#define NODES 128
#define NT    64      // output-column tile per workgroup
#define MCH   16      // sample rows per chunk (one 16-row MFMA tile)
#define PITCH 264     // LDS row pitch in bf16 units (16B-aligned, b128-aligned)

typedef short short8 __attribute__((ext_vector_type(8)));
typedef short short4v __attribute__((ext_vector_type(4)));
typedef float f32x4  __attribute__((ext_vector_type(4)));

struct SMem {
    unsigned short wt[NT * PITCH];   // W^T tile: [c_local][k] bf16 (33.8 KB)
    unsigned short list[BATCH];      // sample ids for this expert (8 KB)
    int cnt;
};

__device__ __forceinline__ unsigned short f2bf(float f) {
    unsigned int u = __builtin_bit_cast(unsigned int, f);
    u += 0x7fffu + ((u >> 16) & 1u);   // round-to-nearest-even
    return (unsigned short)(u >> 16);
}

__device__ __forceinline__ short8 pack8(f32x4 a, f32x4 b) {
    short8 r;
    r[0] = (short)f2bf(a[0]); r[1] = (short)f2bf(a[1]);
    r[2] = (short)f2bf(a[2]); r[3] = (short)f2bf(a[3]);
    r[4] = (short)f2bf(b[0]); r[5] = (short)f2bf(b[1]);
    r[6] = (short)f2bf(b[2]); r[7] = (short)f2bf(b[3]);
    return r;
}

// Gather one chunk's x slice for this lane into registers (issue-only; the
// consuming converts later get compiler-counted vmcnt waits). Tail rows are
// zero-filled: their D rows are discarded by the predicated store.
__device__ __forceinline__ void pf_x(const float* __restrict__ x,
                                     const unsigned short* lst, int m0, int hi,
                                     int ln, int g, f32x4 xr[8][2]) {
    int r = m0 + ln;
    if (r < hi) {
        const float* __restrict__ xp = x + (size_t)lst[r] * INS + g * 8;
        #pragma unroll
        for (int ks = 0; ks < 8; ++ks) {
            xr[ks][0] = *reinterpret_cast<const f32x4*>(xp + ks * 32);
            xr[ks][1] = *reinterpret_cast<const f32x4*>(xp + ks * 32 + 4);
        }
    } else {
        #pragma unroll
        for (int ks = 0; ks < 8; ++ks) {
            xr[ks][0] = (f32x4){0.f, 0.f, 0.f, 0.f};
            xr[ks][1] = (f32x4){0.f, 0.f, 0.f, 0.f};
        }
    }
}

__global__ __launch_bounds__(256, 2) void moe_fwd(
    const float* __restrict__ x, const float* __restrict__ W1,
    const float* __restrict__ b1, const int* __restrict__ nid,
    float* __restrict__ out)
{
    __shared__ SMem sm;
    const int t   = threadIdx.x;
    const int bid = blockIdx.x;
    // XCD-chunked swizzle: all 4 column-quarters of an expert on one XCD.
    const int sub = bid >> 3;              // 0..63 within XCD
    const int e   = (bid & 7) * 16 + (sub >> 2);
    const int c0  = (sub & 3) * NT;

    const int w  = t >> 6;     // wave 0..3 -> 16-col block
    const int l  = t & 63;
    const int g  = l >> 4;     // k-group
    const int ln = l & 15;
    const int cc = c0 + w * 16 + ln;

    if (t == 0) sm.cnt = 0;
    __syncthreads();

    // ---- 1) scan FIRST: nid is 16 KB (L2-amortized across 64 blocks/XCD).
    // Resolves the list dependency before the HBM-heavy W stream is queued.
    const int* __restrict__ idxp = nid + BATCH;
    #pragma unroll
    for (int it = 0; it < BATCH / 256; ++it) {
        int b = it * 256 + t;
        if (idxp[b] == e) {
            int p = atomicAdd(&sm.cnt, 1);
            sm.list[p] = (unsigned short)b;
        }
    }
    asm volatile("s_waitcnt lgkmcnt(0)" ::: "memory");
    __builtin_amdgcn_s_barrier();
    asm volatile("" ::: "memory");

    const int cnt = sm.cnt;
    if (cnt == 0) return;              // uniform across WG

    // ---- 2) issue W loads with FULL cache bypass (sc0 sc1 nt): W is
    // single-use and each 128-B line is consumed by one instruction, so
    // no-allocate avoids evicting ~33 MB of dirty poisoned L2/L3 victims
    // (write-backs that otherwise sit on the read critical path). Inline
    // asm because __builtin_nontemporal_load emits only the weak nt hint.
    const float* __restrict__ wgp = W1 + (size_t)e * (INS * OUTS) + c0;
    const int c4 = (t & 15) * 4;
    const int kq = (t >> 4) * 4;
    f32x4 wr[16];
    #pragma unroll
    for (int pass = 0; pass < 4; ++pass) {
        const int kb = pass * 64 + kq;
        #pragma unroll
        for (int j = 0; j < 4; ++j) {
            const float* ap = &wgp[(size_t)(kb + j) * OUTS + c4];
            asm volatile("global_load_dwordx4 %0, %1, off sc0 sc1 nt"
                         : "=v"(wr[pass * 4 + j]) : "v"(ap));
        }
    }
    const float bval = b1[e * OUTS + cc];

    // ---- 3) issue chunk-0 x gather NOW (compiler loads, cached: x rows are
    // reused 4x across the column-quarter blocks on this XCD). These join
    // the HBM queue behind W; the drain below waits on max, not sum. ----
    f32x4 xA[8][2], xB[8][2];
    pf_x(x, sm.list, 0, cnt, ln, g, xA);

    // ---- 4) drain ALL outstanding vmem (asm loads are invisible to the
    // compiler's vmcnt bookkeeping -> explicit vmcnt(0)), then fence the
    // scheduler so the converts can't hoist above the wait (rule #18). ----
    asm volatile("s_waitcnt vmcnt(0)" ::: "memory");
    __builtin_amdgcn_sched_barrier(0);

    // consume W: transpose 4x4 in regs, stage to LDS [c][k].
    #pragma unroll
    for (int pass = 0; pass < 4; ++pass) {
        const int kb = pass * 64 + kq;
        #pragma unroll
        for (int ci = 0; ci < 4; ++ci) {
            short4v s;
            s[0] = (short)f2bf(wr[pass * 4 + 0][ci]);
            s[1] = (short)f2bf(wr[pass * 4 + 1][ci]);
            s[2] = (short)f2bf(wr[pass * 4 + 2][ci]);
            s[3] = (short)f2bf(wr[pass * 4 + 3][ci]);
            *reinterpret_cast<short4v*>(&sm.wt[(c4 + ci) * PITCH + kb]) = s;
        }
    }
    asm volatile("s_waitcnt lgkmcnt(0)" ::: "memory");
    __builtin_amdgcn_s_barrier();
    asm volatile("" ::: "memory");

    // ---- 5) chunk loop, register-double-buffered x (no LDS, no barriers):
    // chunk c+1's gather is in flight during chunk c's MFMA + stores. ----
    for (int m0 = 0; m0 < cnt; m0 += MCH) {
        const bool more = (m0 + MCH) < cnt;
        if (more) pf_x(x, sm.list, m0 + MCH, cnt, ln, g, xB);

        f32x4 acc = {0.f, 0.f, 0.f, 0.f};
        #pragma unroll
        for (int ks = 0; ks < 8; ++ks) {
            short8 a0 = pack8(xA[ks][0], xA[ks][1]);
            short8 bb = *reinterpret_cast<const short8*>(
                &sm.wt[(w * 16 + ln) * PITCH + ks * 32 + g * 8]);
            acc = __builtin_amdgcn_mfma_f32_16x16x32_bf16(a0, bb, acc, 0, 0, 0);
        }

        // epilogue: D col = lane&15, row = (lane>>4)*4 + q; nt stores.
        #pragma unroll
        for (int q = 0; q < 4; ++q) {
            int rr = m0 + g * 4 + q;
            if (rr < cnt)
                __builtin_nontemporal_store(acc[q] + bval,
                    &out[(size_t)sm.list[rr] * OUTS + cc]);
        }

        if (more) {
            #pragma unroll
            for (int ks = 0; ks < 8; ++ks) {
                xA[ks][0] = xB[ks][0];
                xA[ks][1] = xB[ks][1];
            }
        }
    }
}

extern "C" void kernel_launch(void* const* d_in, const int* in_sizes, int n_in,
                              void* d_out, int out_size, void* d_ws, size_t ws_size,
                              hipStream_t stream) {
    const float* x   = (const float*)d_in[0];
    // d_in[1] = var_vector (unused in forward)
    const float* W1  = (const float*)d_in[2];
    const float* b1  = (const float*)d_in[3];
    const int*   nid = (const int*)d_in[4];
    float* out = (float*)d_out;

    hipLaunchKernelGGL(moe_fwd, dim3(NODES * (OUTS / NT)), dim3(256), 0, stream,
                       x, W1, b1, nid, out);
}

// Round 10
// 21.596 us; speedup vs baseline: 1.0300x; 1.0300x over previous
//
#include <hip/hip_runtime.h>

#define BATCH 4096
#define INS   256
#define OUTS  256
#define NODES 128
#define NT    64      // output-column tile per workgroup
#define MCH   16      // sample rows per chunk (one 16-row MFMA tile)
#define PITCH 264     // LDS row pitch in bf16 units (16B-aligned, b128-aligned)

typedef short short8 __attribute__((ext_vector_type(8)));
typedef short short4v __attribute__((ext_vector_type(4)));
typedef float f32x4  __attribute__((ext_vector_type(4)));

struct SMem {
    unsigned short wt[NT * PITCH];   // W^T tile: [c_local][k] bf16 (33.8 KB)
    unsigned short list[BATCH];      // sample ids for this expert (8 KB)
    int cnt;
};

__device__ __forceinline__ unsigned short f2bf(float f) {
    unsigned int u = __builtin_bit_cast(unsigned int, f);
    u += 0x7fffu + ((u >> 16) & 1u);   // round-to-nearest-even
    return (unsigned short)(u >> 16);
}

__device__ __forceinline__ short8 pack8(f32x4 a, f32x4 b) {
    short8 r;
    r[0] = (short)f2bf(a[0]); r[1] = (short)f2bf(a[1]);
    r[2] = (short)f2bf(a[2]); r[3] = (short)f2bf(a[3]);
    r[4] = (short)f2bf(b[0]); r[5] = (short)f2bf(b[1]);
    r[6] = (short)f2bf(b[2]); r[7] = (short)f2bf(b[3]);
    return r;
}

// Gather one chunk's x slice for this lane into registers (issue-only; the
// consuming converts later get compiler-counted vmcnt waits). Tail rows are
// zero-filled: their D rows are discarded by the predicated store.
__device__ __forceinline__ void pf_x(const float* __restrict__ x,
                                     const unsigned short* lst, int m0, int hi,
                                     int ln, int g, f32x4 xr[8][2]) {
    int r = m0 + ln;
    if (r < hi) {
        const float* __restrict__ xp = x + (size_t)lst[r] * INS + g * 8;
        #pragma unroll
        for (int ks = 0; ks < 8; ++ks) {
            xr[ks][0] = *reinterpret_cast<const f32x4*>(xp + ks * 32);
            xr[ks][1] = *reinterpret_cast<const f32x4*>(xp + ks * 32 + 4);
        }
    } else {
        #pragma unroll
        for (int ks = 0; ks < 8; ++ks) {
            xr[ks][0] = (f32x4){0.f, 0.f, 0.f, 0.f};
            xr[ks][1] = (f32x4){0.f, 0.f, 0.f, 0.f};
        }
    }
}

__global__ __launch_bounds__(256, 2) void moe_fwd(
    const float* __restrict__ x, const float* __restrict__ W1,
    const float* __restrict__ b1, const int* __restrict__ nid,
    float* __restrict__ out)
{
    __shared__ SMem sm;
    const int t   = threadIdx.x;
    const int bid = blockIdx.x;
    // XCD-chunked swizzle: all 4 column-quarters of an expert on one XCD.
    const int sub = bid >> 3;              // 0..63 within XCD
    const int e   = (bid & 7) * 16 + (sub >> 2);
    const int c0  = (sub & 3) * NT;

    const int w  = t >> 6;     // wave 0..3 -> 16-col block
    const int l  = t & 63;
    const int g  = l >> 4;     // k-group
    const int ln = l & 15;
    const int cc = c0 + w * 16 + ln;

    if (t == 0) sm.cnt = 0;
    __syncthreads();

    // ---- 1) scan FIRST: nid is 16 KB (L2-amortized across 64 blocks/XCD).
    // Resolves the list dependency before any HBM-heavy traffic is queued,
    // so the x gather can be ISSUED early instead of after the W drain. ----
    const int* __restrict__ idxp = nid + BATCH;
    #pragma unroll
    for (int it = 0; it < BATCH / 256; ++it) {
        int b = it * 256 + t;
        if (idxp[b] == e) {
            int p = atomicAdd(&sm.cnt, 1);
            sm.list[p] = (unsigned short)b;
        }
    }
    asm volatile("s_waitcnt lgkmcnt(0)" ::: "memory");
    __builtin_amdgcn_s_barrier();
    asm volatile("" ::: "memory");

    const int cnt = sm.cnt;
    if (cnt == 0) return;              // uniform across WG

    // ---- 2) issue W nt loads (float4, full-line, 16 instrs/thread), raw
    // f32 held in registers; do NOT consume yet. nt = evict-first hint:
    // single-use W shouldn't displace dirty poisoned L2/L3 lines. ----
    const float* __restrict__ wgp = W1 + (size_t)e * (INS * OUTS) + c0;
    const int c4 = (t & 15) * 4;
    const int kq = (t >> 4) * 4;
    f32x4 wr[16];
    #pragma unroll
    for (int pass = 0; pass < 4; ++pass) {
        const int kb = pass * 64 + kq;
        #pragma unroll
        for (int j = 0; j < 4; ++j)
            wr[pass * 4 + j] = __builtin_nontemporal_load(
                reinterpret_cast<const f32x4*>(&wgp[(size_t)(kb + j) * OUTS + c4]));
    }
    const float bval = b1[e * OUTS + cc];

    // ---- 3) issue chunk-0 x gather NOW: joins the HBM queue right behind W
    // instead of serially after the whole W drain + convert + barrier. ----
    f32x4 xA[8][2], xB[8][2];
    pf_x(x, sm.list, 0, cnt, ln, g, xA);

    // ---- 4) consume W (counted vmcnt waits: W loads are oldest; the x
    // loads above stay in flight), transpose 4x4 in regs, stage to LDS. ----
    #pragma unroll
    for (int pass = 0; pass < 4; ++pass) {
        const int kb = pass * 64 + kq;
        #pragma unroll
        for (int ci = 0; ci < 4; ++ci) {
            short4v s;
            s[0] = (short)f2bf(wr[pass * 4 + 0][ci]);
            s[1] = (short)f2bf(wr[pass * 4 + 1][ci]);
            s[2] = (short)f2bf(wr[pass * 4 + 2][ci]);
            s[3] = (short)f2bf(wr[pass * 4 + 3][ci]);
            *reinterpret_cast<short4v*>(&sm.wt[(c4 + ci) * PITCH + kb]) = s;
        }
    }
    asm volatile("s_waitcnt lgkmcnt(0)" ::: "memory");
    __builtin_amdgcn_s_barrier();
    asm volatile("" ::: "memory");

    // ---- 5) chunk loop, register-double-buffered x (no LDS, no barriers):
    // chunk c+1's gather is in flight during chunk c's MFMA + stores. ----
    for (int m0 = 0; m0 < cnt; m0 += MCH) {
        const bool more = (m0 + MCH) < cnt;
        if (more) pf_x(x, sm.list, m0 + MCH, cnt, ln, g, xB);

        f32x4 acc = {0.f, 0.f, 0.f, 0.f};
        #pragma unroll
        for (int ks = 0; ks < 8; ++ks) {
            short8 a0 = pack8(xA[ks][0], xA[ks][1]);
            short8 bb = *reinterpret_cast<const short8*>(
                &sm.wt[(w * 16 + ln) * PITCH + ks * 32 + g * 8]);
            acc = __builtin_amdgcn_mfma_f32_16x16x32_bf16(a0, bb, acc, 0, 0, 0);
        }

        // epilogue: D col = lane&15, row = (lane>>4)*4 + q; nt stores.
        #pragma unroll
        for (int q = 0; q < 4; ++q) {
            int rr = m0 + g * 4 + q;
            if (rr < cnt)
                __builtin_nontemporal_store(acc[q] + bval,
                    &out[(size_t)sm.list[rr] * OUTS + cc]);
        }

        if (more) {
            #pragma unroll
            for (int ks = 0; ks < 8; ++ks) {
                xA[ks][0] = xB[ks][0];
                xA[ks][1] = xB[ks][1];
            }
        }
    }
}

extern "C" void kernel_launch(void* const* d_in, const int* in_sizes, int n_in,
                              void* d_out, int out_size, void* d_ws, size_t ws_size,
                              hipStream_t stream) {
    const float* x   = (const float*)d_in[0];
    // d_in[1] = var_vector (unused in forward)
    const float* W1  = (const float*)d_in[2];
    const float* b1  = (const float*)d_in[3];
    const int*   nid = (const int*)d_in[4];
    float* out = (float*)d_out;

    hipLaunchKernelGGL(moe_fwd, dim3(NODES * (OUTS / NT)), dim3(256), 0, stream,
                       x, W1, b1, nid, out);
}